// Round 1
// baseline (93.586 us; speedup 1.0000x reference)
//
#include <hip/hip_runtime.h>
#include <hip/hip_bf16.h>

// Sizes fixed by the reference: B=16, N=2048, F_in=F_out=64.
#define NB 16
#define NN 2048
#define NF 64
#define LOG2E 1.44269504f

typedef __attribute__((ext_vector_type(8))) __bf16 bf16x8;
typedef __attribute__((ext_vector_type(8))) short  short8;
typedef __attribute__((ext_vector_type(4))) float  f32x4;

// g(t) = exp(sigmoid(leakyrelu(t))), evaluated from pre-scaled tp = -log2e * t.
// t >= 0 -> tp <= 0 -> u = tp        = -log2e*leaky(t)
// t <  0 -> tp >  0 -> u = 0.2*tp    = -log2e*0.2*t
__device__ __forceinline__ float evalg(float tp) {
    float u  = fmaf(0.2f, fmaxf(tp, 0.f), fminf(tp, 0.f));
    float ex = __builtin_amdgcn_exp2f(u);              // e^{-leaky}
    float s  = __builtin_amdgcn_rcpf(1.f + ex);        // sigmoid(leaky)
    return __builtin_amdgcn_exp2f(s * LOG2E);          // e^{sigmoid}
}

__device__ __forceinline__ float elu(float v) {
    return v > 0.f ? v : (__builtin_amdgcn_exp2f(v * LOG2E) - 1.f);
}

// ---------------- Pass A: Wh = h@W ; xs = -log2e*(Wh@a1) ; ys = -log2e*(Wh@a2)
__global__ __launch_bounds__(256) void k_prep(const float* __restrict__ h,
                                              const float* __restrict__ W,
                                              const float* __restrict__ a,
                                              float* __restrict__ wh,
                                              float* __restrict__ xs,
                                              float* __restrict__ ys) {
    __shared__ float hb[4][64];
    int w = threadIdx.x >> 6, lane = threadIdx.x & 63;
    int r = blockIdx.x * 4 + w;                 // row in [0, B*N)
    hb[w][lane] = h[r * 64 + lane];
    float acc = 0.f;
#pragma unroll
    for (int k = 0; k < 64; k++) acc = fmaf(hb[w][k], W[k * 64 + lane], acc);
    wh[r * 64 + lane] = acc;
    float xv = acc * a[lane];
    float yv = acc * a[64 + lane];
#pragma unroll
    for (int m = 32; m; m >>= 1) {
        xv += __shfl_xor(xv, m, 64);
        yv += __shfl_xor(yv, m, 64);
    }
    if (lane == 0) {
        xs[r] = -LOG2E * xv;
        ys[r] = -LOG2E * yv;
    }
}

// ---------------- Pass B: column-sum partials  dpart[isp][b][j] = sum over 256 i's of g(x_i+y_j)
__global__ __launch_bounds__(256) void k_colsum(const float* __restrict__ xs,
                                                const float* __restrict__ ys,
                                                float* __restrict__ dpart) {
    __shared__ float xb[256];
    int tid = threadIdx.x;
    int bx  = blockIdx.x;
    int jb  = bx & 7;          // N/256 = 8 j-chunks
    int isp = (bx >> 3) & 7;   // 8-way i split
    int b   = bx >> 6;
    xb[tid] = xs[b * NN + isp * 256 + tid];
    __syncthreads();
    float yv  = ys[b * NN + jb * 256 + tid];
    float acc = 0.f;
#pragma unroll 4
    for (int i4 = 0; i4 < 64; i4++) {
        float4 xv = *reinterpret_cast<const float4*>(&xb[i4 * 4]);
        acc += evalg(xv.x + yv);
        acc += evalg(xv.y + yv);
        acc += evalg(xv.z + yv);
        acc += evalg(xv.w + yv);
    }
    dpart[isp * (NB * NN) + b * NN + jb * 256 + tid] = acc;
}

// ---------------- Pass B-reduce: D = sum of 8 partials
__global__ __launch_bounds__(256) void k_dreduce(const float* __restrict__ dpart,
                                                 float* __restrict__ D) {
    int g = blockIdx.x * 256 + threadIdx.x;    // [0, B*N)
    float s = 0.f;
#pragma unroll
    for (int p = 0; p < 8; p++) s += dpart[p * (NB * NN) + g];
    D[g] = s;
}

// ---------------- Pass B2: V = Wh / D  ->  bf16, pre-arranged in MFMA B-fragment order
// vfrag layout: [b][ks(64)][nt(4)][lane(64)] x 8 bf16 (16B per lane slot)
// B-frag convention (16x16x32): col = lane&15, k = (lane>>4)*8 + e
__global__ __launch_bounds__(256) void k_vfrag(const float* __restrict__ wh,
                                               const float* __restrict__ D,
                                               uint4* __restrict__ vfrag) {
    int g    = blockIdx.x * 256 + threadIdx.x;   // [0, B*64*4*64)
    int lane = g & 63;
    int nt   = (g >> 6) & 3;
    int ks   = (g >> 8) & 63;
    int b    = g >> 14;
    int kb   = ks * 32 + (lane >> 4) * 8;
    int f    = nt * 16 + (lane & 15);
    const float* whp = wh + (b * NN + kb) * 64 + f;
    const float* Dp  = D + b * NN + kb;
    short8 o;
#pragma unroll
    for (int e = 0; e < 8; e++) {
        float v   = whp[e * 64] * __builtin_amdgcn_rcpf(Dp[e]);
        __bf16 bv = (__bf16)v;
        o[e]      = __builtin_bit_cast(short, bv);
    }
    vfrag[g] = __builtin_bit_cast(uint4, o);
}

// ---------------- Pass C: out = ELU( E @ V ), E generated in-register per MFMA A-fragment.
// Each wave: 16 rows x 64 cols output; loop 64 K-steps of 32.
// A-frag (16x32): row = lane&15, k = (lane>>4)*8 + e
// C/D frag:       col = lane&15, row = (lane>>4)*4 + reg   [verified layout]
__global__ __launch_bounds__(256) void k_attn(const float* __restrict__ xs,
                                              const float* __restrict__ ys,
                                              const uint4* __restrict__ vfrag,
                                              float* __restrict__ out) {
    int b  = blockIdx.x >> 5;     // 32 i-blocks per batch
    int ib = blockIdx.x & 31;
    int w  = threadIdx.x >> 6, lane = threadIdx.x & 63;
    int il = lane & 15, kg = lane >> 4;
    int ibase = ib * 64 + w * 16;

    float xv = xs[b * NN + ibase + il];
    const float* ysb = ys + b * NN;
    const uint4* vfb = vfrag + b * 16384 + lane;

    f32x4 acc0 = {0.f, 0.f, 0.f, 0.f};
    f32x4 acc1 = {0.f, 0.f, 0.f, 0.f};
    f32x4 acc2 = {0.f, 0.f, 0.f, 0.f};
    f32x4 acc3 = {0.f, 0.f, 0.f, 0.f};

    for (int ks = 0; ks < 64; ks++) {
        const float* yp = ysb + ks * 32 + kg * 8;
        float4 ya = *reinterpret_cast<const float4*>(yp);
        float4 yb = *reinterpret_cast<const float4*>(yp + 4);
        float wv[8];
        wv[0] = evalg(xv + ya.x);
        wv[1] = evalg(xv + ya.y);
        wv[2] = evalg(xv + ya.z);
        wv[3] = evalg(xv + ya.w);
        wv[4] = evalg(xv + yb.x);
        wv[5] = evalg(xv + yb.y);
        wv[6] = evalg(xv + yb.z);
        wv[7] = evalg(xv + yb.w);
        bf16x8 af;
#pragma unroll
        for (int e = 0; e < 8; e++) af[e] = (__bf16)wv[e];

        const uint4* vp = vfb + ks * 256;
        bf16x8 b0 = __builtin_bit_cast(bf16x8, vp[0]);
        bf16x8 b1 = __builtin_bit_cast(bf16x8, vp[64]);
        bf16x8 b2 = __builtin_bit_cast(bf16x8, vp[128]);
        bf16x8 b3 = __builtin_bit_cast(bf16x8, vp[192]);

        acc0 = __builtin_amdgcn_mfma_f32_16x16x32_bf16(af, b0, acc0, 0, 0, 0);
        acc1 = __builtin_amdgcn_mfma_f32_16x16x32_bf16(af, b1, acc1, 0, 0, 0);
        acc2 = __builtin_amdgcn_mfma_f32_16x16x32_bf16(af, b2, acc2, 0, 0, 0);
        acc3 = __builtin_amdgcn_mfma_f32_16x16x32_bf16(af, b3, acc3, 0, 0, 0);
    }

    int rbase = b * NN + ibase + kg * 4;
#pragma unroll
    for (int r = 0; r < 4; r++) {
        float* orow = out + (rbase + r) * 64 + il;
        orow[0]  = elu(acc0[r]);
        orow[16] = elu(acc1[r]);
        orow[32] = elu(acc2[r]);
        orow[48] = elu(acc3[r]);
    }
}

extern "C" void kernel_launch(void* const* d_in, const int* in_sizes, int n_in,
                              void* d_out, int out_size, void* d_ws, size_t ws_size,
                              hipStream_t stream) {
    const float* h = (const float*)d_in[0];
    const float* W = (const float*)d_in[1];
    const float* a = (const float*)d_in[2];
    float* out = (float*)d_out;

    // workspace layout (floats), ~14 MB total
    float* wh    = (float*)d_ws;                   // B*N*64   = 2,097,152 f
    float* xs    = wh + NB * NN * NF;              // B*N      =    32,768 f
    float* ys    = xs + NB * NN;                   // B*N
    float* dpart = ys + NB * NN;                   // 8*B*N    =   262,144 f
    float* Dv    = dpart + 8 * NB * NN;            // B*N
    uint4* vfrag = (uint4*)(Dv + NB * NN);         // B*N*64 bf16 = 4 MB (16B aligned)

    k_prep<<<dim3(NB * NN / 4), dim3(256), 0, stream>>>(h, W, a, wh, xs, ys);
    k_colsum<<<dim3(NB * 8 * (NN / 256)), dim3(256), 0, stream>>>(xs, ys, dpart);
    k_dreduce<<<dim3(NB * NN / 256), dim3(256), 0, stream>>>(dpart, Dv);
    k_vfrag<<<dim3(NB * NN * NF / 8 / 256), dim3(256), 0, stream>>>(wh, Dv, vfrag);
    k_attn<<<dim3(NB * 32), dim3(256), 0, stream>>>(xs, ys, vfrag, out);
}

// Round 2
// 90.826 us; speedup vs baseline: 1.0304x; 1.0304x over previous
//
#include <hip/hip_runtime.h>
#include <hip/hip_bf16.h>

// Sizes fixed by the reference: B=16, N=2048, F_in=F_out=64.
#define NB 16
#define NN 2048
#define NF 64
#define LOG2E 1.44269504f
#define KSPLIT 4          // k_attn K-split factor
#define ISPLIT 16         // k_colsum i-split factor

typedef __attribute__((ext_vector_type(8))) __bf16 bf16x8;
typedef __attribute__((ext_vector_type(8))) short  short8;
typedef __attribute__((ext_vector_type(4))) float  f32x4;

// g(t) = exp(sigmoid(leakyrelu(t))), evaluated from pre-scaled tp = -log2e * t.
// In the negated-scaled domain, leaky becomes: u = min(tp, 0.2*tp)
//   t >= 0 -> tp <= 0 -> min picks tp        (= -log2e*t)
//   t <  0 -> tp >  0 -> min picks 0.2*tp    (= -log2e*0.2*t)
__device__ __forceinline__ float evalg(float tp) {
    float u  = fminf(tp, 0.2f * tp);
    float ex = __builtin_amdgcn_exp2f(u);              // e^{-leaky}
    float s  = __builtin_amdgcn_rcpf(1.f + ex);        // sigmoid(leaky)
    return __builtin_amdgcn_exp2f(s * LOG2E);          // e^{sigmoid}
}

__device__ __forceinline__ float elu(float v) {
    return v > 0.f ? v : (__builtin_amdgcn_exp2f(v * LOG2E) - 1.f);
}

// ---------------- Pass A: Wh = h@W ; xs = -log2e*(Wh@a1) ; ys = -log2e*(Wh@a2)
__global__ __launch_bounds__(256) void k_prep(const float* __restrict__ h,
                                              const float* __restrict__ W,
                                              const float* __restrict__ a,
                                              float* __restrict__ wh,
                                              float* __restrict__ xs,
                                              float* __restrict__ ys) {
    __shared__ float hb[4][64];
    int w = threadIdx.x >> 6, lane = threadIdx.x & 63;
    int r = blockIdx.x * 4 + w;                 // row in [0, B*N)
    hb[w][lane] = h[r * 64 + lane];
    float acc = 0.f;
#pragma unroll
    for (int k = 0; k < 64; k++) acc = fmaf(hb[w][k], W[k * 64 + lane], acc);
    wh[r * 64 + lane] = acc;
    float xv = acc * a[lane];
    float yv = acc * a[64 + lane];
#pragma unroll
    for (int m = 32; m; m >>= 1) {
        xv += __shfl_xor(xv, m, 64);
        yv += __shfl_xor(yv, m, 64);
    }
    if (lane == 0) {
        xs[r] = -LOG2E * xv;
        ys[r] = -LOG2E * yv;
    }
}

// ---------------- Pass B: column-sum partials  dpart[isp][b][j] = sum over 128 i's of g(x_i+y_j)
__global__ __launch_bounds__(256) void k_colsum(const float* __restrict__ xs,
                                                const float* __restrict__ ys,
                                                float* __restrict__ dpart) {
    __shared__ float xb[128];
    int tid = threadIdx.x;
    int bx  = blockIdx.x;
    int jb  = bx & 7;            // N/256 = 8 j-chunks
    int isp = (bx >> 3) & 15;    // 16-way i split (128 i's each)
    int b   = bx >> 7;
    if (tid < 128) xb[tid] = xs[b * NN + isp * 128 + tid];
    __syncthreads();
    float yv  = ys[b * NN + jb * 256 + tid];
    float acc = 0.f;
#pragma unroll 4
    for (int i4 = 0; i4 < 32; i4++) {
        float4 xv = *reinterpret_cast<const float4*>(&xb[i4 * 4]);
        acc += evalg(xv.x + yv);
        acc += evalg(xv.y + yv);
        acc += evalg(xv.z + yv);
        acc += evalg(xv.w + yv);
    }
    dpart[isp * (NB * NN) + b * NN + jb * 256 + tid] = acc;
}

// ---------------- Pass B-reduce: D = sum of 16 partials
__global__ __launch_bounds__(256) void k_dreduce(const float* __restrict__ dpart,
                                                 float* __restrict__ D) {
    int g = blockIdx.x * 256 + threadIdx.x;    // [0, B*N)
    float s = 0.f;
#pragma unroll
    for (int p = 0; p < ISPLIT; p++) s += dpart[p * (NB * NN) + g];
    D[g] = s;
}

// ---------------- Pass B2: V = Wh / D  ->  bf16, pre-arranged in MFMA B-fragment order
// vfrag layout: [b][ks(64)][nt(4)][lane(64)] x 8 bf16 (16B per lane slot)
// B-frag convention (16x16x32): col = lane&15, k = (lane>>4)*8 + e
__global__ __launch_bounds__(256) void k_vfrag(const float* __restrict__ wh,
                                               const float* __restrict__ D,
                                               uint4* __restrict__ vfrag) {
    int g    = blockIdx.x * 256 + threadIdx.x;   // [0, B*64*4*64)
    int lane = g & 63;
    int nt   = (g >> 6) & 3;
    int ks   = (g >> 8) & 63;
    int b    = g >> 14;
    int kb   = ks * 32 + (lane >> 4) * 8;
    int f    = nt * 16 + (lane & 15);
    const float* whp = wh + (b * NN + kb) * 64 + f;
    const float* Dp  = D + b * NN + kb;
    short8 o;
#pragma unroll
    for (int e = 0; e < 8; e++) {
        float v   = whp[e * 64] * __builtin_amdgcn_rcpf(Dp[e]);
        __bf16 bv = (__bf16)v;
        o[e]      = __builtin_bit_cast(short, bv);
    }
    vfrag[g] = __builtin_bit_cast(uint4, o);
}

// ---------------- Pass C: partial = E @ V over a K-slice; E generated in-register.
// Each wave: 16 rows x 64 cols output; 16 K-steps of 32 (KSPLIT=4 slices).
// A-frag (16x32): row = lane&15, k = (lane>>4)*8 + e
// C/D frag:       col = lane&15, row = (lane>>4)*4 + reg   [verified layout]
__global__ __launch_bounds__(256) void k_attn(const float* __restrict__ xs,
                                              const float* __restrict__ ys,
                                              const uint4* __restrict__ vfrag,
                                              float* __restrict__ part) {
    int bx = blockIdx.x;
    int kz = bx >> 9;             // K-slice [0,4)
    int tb = bx & 511;
    int b  = tb >> 5;             // batch
    int ib = tb & 31;             // 32 i-blocks per batch
    int w  = threadIdx.x >> 6, lane = threadIdx.x & 63;
    int il = lane & 15, kg = lane >> 4;
    int ibase = ib * 64 + w * 16;

    float xv = xs[b * NN + ibase + il];
    const float* ysb = ys + b * NN;
    const uint4* vfb = vfrag + b * 16384 + lane;

    f32x4 acc0 = {0.f, 0.f, 0.f, 0.f};
    f32x4 acc1 = {0.f, 0.f, 0.f, 0.f};
    f32x4 acc2 = {0.f, 0.f, 0.f, 0.f};
    f32x4 acc3 = {0.f, 0.f, 0.f, 0.f};

    for (int ks = kz * 16; ks < kz * 16 + 16; ks++) {
        const float* yp = ysb + ks * 32 + kg * 8;
        float4 ya = *reinterpret_cast<const float4*>(yp);
        float4 yb = *reinterpret_cast<const float4*>(yp + 4);
        float wv[8];
        wv[0] = evalg(xv + ya.x);
        wv[1] = evalg(xv + ya.y);
        wv[2] = evalg(xv + ya.z);
        wv[3] = evalg(xv + ya.w);
        wv[4] = evalg(xv + yb.x);
        wv[5] = evalg(xv + yb.y);
        wv[6] = evalg(xv + yb.z);
        wv[7] = evalg(xv + yb.w);
        bf16x8 af;
#pragma unroll
        for (int e = 0; e < 8; e++) af[e] = (__bf16)wv[e];

        const uint4* vp = vfb + ks * 256;
        bf16x8 b0 = __builtin_bit_cast(bf16x8, vp[0]);
        bf16x8 b1 = __builtin_bit_cast(bf16x8, vp[64]);
        bf16x8 b2 = __builtin_bit_cast(bf16x8, vp[128]);
        bf16x8 b3 = __builtin_bit_cast(bf16x8, vp[192]);

        acc0 = __builtin_amdgcn_mfma_f32_16x16x32_bf16(af, b0, acc0, 0, 0, 0);
        acc1 = __builtin_amdgcn_mfma_f32_16x16x32_bf16(af, b1, acc1, 0, 0, 0);
        acc2 = __builtin_amdgcn_mfma_f32_16x16x32_bf16(af, b2, acc2, 0, 0, 0);
        acc3 = __builtin_amdgcn_mfma_f32_16x16x32_bf16(af, b3, acc3, 0, 0, 0);
    }

    float* pslice = part + kz * (NB * NN * NF);
    int rbase = b * NN + ibase + kg * 4;
#pragma unroll
    for (int r = 0; r < 4; r++) {
        float* orow = pslice + (rbase + r) * 64 + il;
        orow[0]  = acc0[r];
        orow[16] = acc1[r];
        orow[32] = acc2[r];
        orow[48] = acc3[r];
    }
}

// ---------------- Pass C-reduce: out = ELU( sum of 4 K-slice partials )
__global__ __launch_bounds__(256) void k_finish(const float* __restrict__ part,
                                                float* __restrict__ out) {
    int g = blockIdx.x * 256 + threadIdx.x;    // float4 index, [0, B*N*64/4)
    const int M = NB * NN * NF / 4;
    const float4* p = reinterpret_cast<const float4*>(part);
    float4 s0 = p[g];
    float4 s1 = p[g + M];
    float4 s2 = p[g + 2 * M];
    float4 s3 = p[g + 3 * M];
    float4 r;
    r.x = elu(s0.x + s1.x + s2.x + s3.x);
    r.y = elu(s0.y + s1.y + s2.y + s3.y);
    r.z = elu(s0.z + s1.z + s2.z + s3.z);
    r.w = elu(s0.w + s1.w + s2.w + s3.w);
    reinterpret_cast<float4*>(out)[g] = r;
}

extern "C" void kernel_launch(void* const* d_in, const int* in_sizes, int n_in,
                              void* d_out, int out_size, void* d_ws, size_t ws_size,
                              hipStream_t stream) {
    const float* h = (const float*)d_in[0];
    const float* W = (const float*)d_in[1];
    const float* a = (const float*)d_in[2];
    float* out = (float*)d_out;

    // workspace layout (floats), ~55 MB total
    float* wh    = (float*)d_ws;                   // B*N*64   = 2,097,152 f
    float* xs    = wh + NB * NN * NF;              // B*N      =    32,768 f
    float* ys    = xs + NB * NN;                   // B*N
    float* dpart = ys + NB * NN;                   // 16*B*N   =   524,288 f
    float* Dv    = dpart + ISPLIT * NB * NN;       // B*N
    uint4* vfrag = (uint4*)(Dv + NB * NN);         // B*N*64 bf16 = 4 MB (16B aligned)
    float* part  = (float*)(vfrag + NB * NN * NF / 8);  // 4*B*N*64 f32 = 32 MB

    k_prep<<<dim3(NB * NN / 4), dim3(256), 0, stream>>>(h, W, a, wh, xs, ys);
    k_colsum<<<dim3(NB * ISPLIT * (NN / 256)), dim3(256), 0, stream>>>(xs, ys, dpart);
    k_dreduce<<<dim3(NB * NN / 256), dim3(256), 0, stream>>>(dpart, Dv);
    k_vfrag<<<dim3(NB * NN * NF / 8 / 256), dim3(256), 0, stream>>>(wh, Dv, vfrag);
    k_attn<<<dim3(NB * 32 * KSPLIT), dim3(256), 0, stream>>>(xs, ys, vfrag, part);
    k_finish<<<dim3(NB * NN * NF / 4 / 256), dim3(256), 0, stream>>>(part, out);
}

// Round 3
// 81.377 us; speedup vs baseline: 1.1500x; 1.1161x over previous
//
#include <hip/hip_runtime.h>
#include <hip/hip_bf16.h>

// Sizes fixed by the reference: B=16, N=2048, F_in=F_out=64.
#define NB 16
#define NN 2048
#define NF 64
#define LOG2E 1.44269504f
#define ISPLIT 16         // k_colsum i-split factor

typedef __attribute__((ext_vector_type(8))) __bf16 bf16x8;
typedef __attribute__((ext_vector_type(8))) short  short8;
typedef __attribute__((ext_vector_type(4))) float  f32x4;

// g(t) = exp(sigmoid(leakyrelu(t))), evaluated from pre-scaled tp = -log2e * t.
// In the negated-scaled domain, leaky becomes: u = min(tp, 0.2*tp)
__device__ __forceinline__ float evalg(float tp) {
    float u  = fminf(tp, 0.2f * tp);
    float ex = __builtin_amdgcn_exp2f(u);              // e^{-leaky}
    float s  = __builtin_amdgcn_rcpf(1.f + ex);        // sigmoid(leaky)
    return __builtin_amdgcn_exp2f(s * LOG2E);          // e^{sigmoid}
}

__device__ __forceinline__ float elu(float v) {
    return v > 0.f ? v : (__builtin_amdgcn_exp2f(v * LOG2E) - 1.f);
}

// ---------------- Pass A: Wh = h@W ; xs = -log2e*(Wh@a1) ; ys = -log2e*(Wh@a2)
__global__ __launch_bounds__(256) void k_prep(const float* __restrict__ h,
                                              const float* __restrict__ W,
                                              const float* __restrict__ a,
                                              float* __restrict__ wh,
                                              float* __restrict__ xs,
                                              float* __restrict__ ys) {
    __shared__ float hb[4][64];
    int w = threadIdx.x >> 6, lane = threadIdx.x & 63;
    int r = blockIdx.x * 4 + w;                 // row in [0, B*N)
    hb[w][lane] = h[r * 64 + lane];
    float acc = 0.f;
#pragma unroll
    for (int k = 0; k < 64; k++) acc = fmaf(hb[w][k], W[k * 64 + lane], acc);
    wh[r * 64 + lane] = acc;
    float xv = acc * a[lane];
    float yv = acc * a[64 + lane];
#pragma unroll
    for (int m = 32; m; m >>= 1) {
        xv += __shfl_xor(xv, m, 64);
        yv += __shfl_xor(yv, m, 64);
    }
    if (lane == 0) {
        xs[r] = -LOG2E * xv;
        ys[r] = -LOG2E * yv;
    }
}

// ---------------- Pass B: column-sum partials  dpart[isp][b][j] = sum over 128 i's of g(x_i+y_j)
__global__ __launch_bounds__(256) void k_colsum(const float* __restrict__ xs,
                                                const float* __restrict__ ys,
                                                float* __restrict__ dpart) {
    __shared__ float xb[128];
    int tid = threadIdx.x;
    int bx  = blockIdx.x;
    int jb  = bx & 7;            // N/256 = 8 j-chunks
    int isp = (bx >> 3) & 15;    // 16-way i split (128 i's each)
    int b   = bx >> 7;
    if (tid < 128) xb[tid] = xs[b * NN + isp * 128 + tid];
    __syncthreads();
    float yv  = ys[b * NN + jb * 256 + tid];
    float acc = 0.f;
#pragma unroll 4
    for (int i4 = 0; i4 < 32; i4++) {
        float4 xv = *reinterpret_cast<const float4*>(&xb[i4 * 4]);
        acc += evalg(xv.x + yv);
        acc += evalg(xv.y + yv);
        acc += evalg(xv.z + yv);
        acc += evalg(xv.w + yv);
    }
    dpart[isp * (NB * NN) + b * NN + jb * 256 + tid] = acc;
}

// ---------------- Pass B2 (fused D-reduce + V-frag): block per (b, ks) handles 32 rows.
// D[row] = sum of 16 dpart slices; V = Wh / D -> bf16 in MFMA B-fragment order.
// vfrag layout: [b][ks(64)][nt(4)][lane(64)] x 8 bf16; B-frag: col = lane&15, k = (lane>>4)*8 + e
__global__ __launch_bounds__(256) void k_vfragD(const float* __restrict__ wh,
                                                const float* __restrict__ dpart,
                                                uint4* __restrict__ vfrag) {
    __shared__ float pred[8][32];
    __shared__ float dinv[32];
    int bx = blockIdx.x;
    int ks = bx & 63;
    int b  = bx >> 6;
    int t  = threadIdx.x;
    {   // stage 1: 16 partials -> 8 in LDS
        int p = t >> 5, r = t & 31;
        int rowg = b * NN + ks * 32 + r;
        pred[p][r] = dpart[p * (NB * NN) + rowg] + dpart[(p + 8) * (NB * NN) + rowg];
    }
    __syncthreads();
    if (t < 32) {   // stage 2: finish the sum, invert
        float s = 0.f;
#pragma unroll
        for (int p2 = 0; p2 < 8; p2++) s += pred[p2][t];
        dinv[t] = __builtin_amdgcn_rcpf(s);
    }
    __syncthreads();
    int lane = t & 63, nt = t >> 6;
    int kg = lane >> 4, il = lane & 15;
    const float* whp = wh + (b * NN + ks * 32 + kg * 8) * 64 + nt * 16 + il;
    short8 o;
#pragma unroll
    for (int e = 0; e < 8; e++) {
        float v   = whp[e * 64] * dinv[kg * 8 + e];
        __bf16 bv = (__bf16)v;
        o[e]      = __builtin_bit_cast(short, bv);
    }
    vfrag[((b * 64 + ks) * 4 + nt) * 64 + lane] = __builtin_bit_cast(uint4, o);
}

// ---------------- Pass C: out = ELU( E @ V ), fully fused.
// Block = 1024 threads = 16 waves = 4 row-waves x 4 K-slices; block owns 64x64 output tile.
// A-frag (16x32): row = lane&15, k = (lane>>4)*8 + e
// C/D frag:       col = lane&15, row = (lane>>4)*4 + reg   [verified layout]
__global__ __launch_bounds__(1024, 8) void k_attn(const float* __restrict__ xs,
                                                  const float* __restrict__ ys,
                                                  const uint4* __restrict__ vfrag,
                                                  float* __restrict__ out) {
    __shared__ float red[3][4][16][65];   // [kz-1][wr][local row][col(+pad)]
    int b  = blockIdx.x >> 5;
    int ib = blockIdx.x & 31;
    int w  = threadIdx.x >> 6, lane = threadIdx.x & 63;
    int kz = w >> 2, wr = w & 3;
    int il = lane & 15, kg = lane >> 4;
    int ibase = ib * 64 + wr * 16;

    float xv = xs[b * NN + ibase + il];
    const float* ysb = ys + b * NN;
    const uint4* vfb = vfrag + b * 16384 + lane;

    f32x4 acc0 = {0.f, 0.f, 0.f, 0.f};
    f32x4 acc1 = {0.f, 0.f, 0.f, 0.f};
    f32x4 acc2 = {0.f, 0.f, 0.f, 0.f};
    f32x4 acc3 = {0.f, 0.f, 0.f, 0.f};

    for (int ks = kz * 16; ks < kz * 16 + 16; ks++) {
        const float* yp = ysb + ks * 32 + kg * 8;
        float4 ya = *reinterpret_cast<const float4*>(yp);
        float4 yb = *reinterpret_cast<const float4*>(yp + 4);
        float wv[8];
        wv[0] = evalg(xv + ya.x);
        wv[1] = evalg(xv + ya.y);
        wv[2] = evalg(xv + ya.z);
        wv[3] = evalg(xv + ya.w);
        wv[4] = evalg(xv + yb.x);
        wv[5] = evalg(xv + yb.y);
        wv[6] = evalg(xv + yb.z);
        wv[7] = evalg(xv + yb.w);
        bf16x8 af;
#pragma unroll
        for (int e = 0; e < 8; e++) af[e] = (__bf16)wv[e];

        const uint4* vp = vfb + ks * 256;
        bf16x8 b0 = __builtin_bit_cast(bf16x8, vp[0]);
        bf16x8 b1 = __builtin_bit_cast(bf16x8, vp[64]);
        bf16x8 b2 = __builtin_bit_cast(bf16x8, vp[128]);
        bf16x8 b3 = __builtin_bit_cast(bf16x8, vp[192]);

        acc0 = __builtin_amdgcn_mfma_f32_16x16x32_bf16(af, b0, acc0, 0, 0, 0);
        acc1 = __builtin_amdgcn_mfma_f32_16x16x32_bf16(af, b1, acc1, 0, 0, 0);
        acc2 = __builtin_amdgcn_mfma_f32_16x16x32_bf16(af, b2, acc2, 0, 0, 0);
        acc3 = __builtin_amdgcn_mfma_f32_16x16x32_bf16(af, b3, acc3, 0, 0, 0);
    }

    if (kz > 0) {
#pragma unroll
        for (int r = 0; r < 4; r++) {
            float* rp = &red[kz - 1][wr][kg * 4 + r][il];
            rp[0]  = acc0[r];
            rp[16] = acc1[r];
            rp[32] = acc2[r];
            rp[48] = acc3[r];
        }
    }
    __syncthreads();
    if (kz == 0) {
        int rbase = b * NN + ibase + kg * 4;
#pragma unroll
        for (int r = 0; r < 4; r++) {
            const float* r0 = &red[0][wr][kg * 4 + r][il];
            const float* r1 = &red[1][wr][kg * 4 + r][il];
            const float* r2 = &red[2][wr][kg * 4 + r][il];
            float* orow = out + (rbase + r) * 64 + il;
            orow[0]  = elu(acc0[r] + r0[0]  + r1[0]  + r2[0]);
            orow[16] = elu(acc1[r] + r0[16] + r1[16] + r2[16]);
            orow[32] = elu(acc2[r] + r0[32] + r1[32] + r2[32]);
            orow[48] = elu(acc3[r] + r0[48] + r1[48] + r2[48]);
        }
    }
}

extern "C" void kernel_launch(void* const* d_in, const int* in_sizes, int n_in,
                              void* d_out, int out_size, void* d_ws, size_t ws_size,
                              hipStream_t stream) {
    const float* h = (const float*)d_in[0];
    const float* W = (const float*)d_in[1];
    const float* a = (const float*)d_in[2];
    float* out = (float*)d_out;

    // workspace layout (floats), ~15 MB total
    float* wh    = (float*)d_ws;                   // B*N*64   = 2,097,152 f
    float* xs    = wh + NB * NN * NF;              // B*N      =    32,768 f
    float* ys    = xs + NB * NN;                   // B*N
    float* dpart = ys + NB * NN;                   // 16*B*N   =   524,288 f
    uint4* vfrag = (uint4*)(dpart + ISPLIT * NB * NN);  // B*N*64 bf16 = 4 MB

    k_prep<<<dim3(NB * NN / 4), dim3(256), 0, stream>>>(h, W, a, wh, xs, ys);
    k_colsum<<<dim3(NB * ISPLIT * (NN / 256)), dim3(256), 0, stream>>>(xs, ys, dpart);
    k_vfragD<<<dim3(NB * 64), dim3(256), 0, stream>>>(wh, dpart, vfrag);
    k_attn<<<dim3(NB * 32), dim3(1024), 0, stream>>>(xs, ys, vfrag, out);
}